// Round 6
// baseline (355.879 us; speedup 1.0000x reference)
//
#include <hip/hip_runtime.h>
#include <cmath>

#define C_DIM   1024
#define H_DIM   16
#define HD      64
#define N_TOK   2048
#define M_TOK   4096
#define LOG2E   1.44269504088896340736f

typedef _Float16 f16;
typedef __attribute__((ext_vector_type(8))) _Float16 f16x8;
typedef __attribute__((ext_vector_type(4))) _Float16 f16x4;
typedef __attribute__((ext_vector_type(4))) float    f32x4;

// async global->LDS, 16B per lane; LDS dest = wave-uniform base + lane*16
__device__ __forceinline__ void gl_lds16(const void* g, void* l) {
  __builtin_amdgcn_global_load_lds((const __attribute__((address_space(1))) void*)g,
                                   (__attribute__((address_space(3))) void*)l, 16, 0, 0);
}

// ---------------------------------------------------------------------------
// fp32 -> fp16 convert: x (4.19M), qkv_w (3.15M), proj_w (1.05M), float4/thread
// ---------------------------------------------------------------------------
#define CVT_X4 1048576
#define CVT_W4 786432
#define CVT_P4 262144
__global__ __launch_bounds__(256) void cvt_all(const float* __restrict__ x,
                                               const float* __restrict__ w1,
                                               const float* __restrict__ w2,
                                               f16* __restrict__ xh,
                                               f16* __restrict__ wh1,
                                               f16* __restrict__ wh2) {
  const int i = blockIdx.x * 256 + threadIdx.x;
  const float4* src; f16* dst; int off;
  if (i < CVT_X4)               { src = (const float4*)x;  dst = xh;  off = i; }
  else if (i < CVT_X4 + CVT_W4) { src = (const float4*)w1; dst = wh1; off = i - CVT_X4; }
  else                          { src = (const float4*)w2; dst = wh2; off = i - CVT_X4 - CVT_W4; }
  const float4 v = src[off];
  union { f16 h[4]; ushort4 u; } p;
  p.h[0] = (f16)v.x; p.h[1] = (f16)v.y; p.h[2] = (f16)v.z; p.h[3] = (f16)v.w;
  *(ushort4*)(dst + (size_t)off * 4) = p.u;
}

// ---------------------------------------------------------------------------
// Shared MFMA NT-GEMM mainloop: 128x128 tile, BK=32, 4 waves (2x2), fp16.
// ---------------------------------------------------------------------------
__device__ __forceinline__ void gemm_mainloop(const f16* __restrict__ A,
                                              const f16* __restrict__ B,
                                              int K, int bm, int bn,
                                              f16* As, f16* Bs,
                                              f32x4 (&acc)[4][4]) {
  const int tid  = threadIdx.x;
  const int w    = tid >> 6, lane = tid & 63;
  const int wm   = w >> 1,   wn   = w & 1;
  const int ln   = lane & 15, quad = lane >> 4;
  const int sr   = lane >> 2;
  const int sc   = (lane & 3) << 3;

  const f16* Ag0 = A + (size_t)(bm + w * 16 + sr) * K + sc;
  const f16* Ag1 = A + (size_t)(bm + (w + 4) * 16 + sr) * K + sc;
  const f16* Bg0 = B + (size_t)(bn + w * 16 + sr) * K + sc;
  const f16* Bg1 = B + (size_t)(bn + (w + 4) * 16 + sr) * K + sc;
  f16* Al0 = As + (w * 16) * 32;
  f16* Al1 = As + ((w + 4) * 16) * 32;
  f16* Bl0 = Bs + (w * 16) * 32;
  f16* Bl1 = Bs + ((w + 4) * 16) * 32;

  for (int k0 = 0; k0 < K; k0 += 32) {
    __syncthreads();
    gl_lds16(Ag0 + k0, Al0);
    gl_lds16(Ag1 + k0, Al1);
    gl_lds16(Bg0 + k0, Bl0);
    gl_lds16(Bg1 + k0, Bl1);
    __syncthreads();
    f16x8 af[4], bf[4];
#pragma unroll
    for (int fm = 0; fm < 4; ++fm)
      af[fm] = *(const f16x8*)&As[(wm * 64 + fm * 16 + ln) * 32 + quad * 8];
#pragma unroll
    for (int fn = 0; fn < 4; ++fn)
      bf[fn] = *(const f16x8*)&Bs[(wn * 64 + fn * 16 + ln) * 32 + quad * 8];
#pragma unroll
    for (int fm = 0; fm < 4; ++fm)
#pragma unroll
      for (int fn = 0; fn < 4; ++fn)
        acc[fm][fn] = __builtin_amdgcn_mfma_f32_16x16x32_f16(af[fm], bf[fn], acc[fm][fn], 0, 0, 0);
  }
}

// ---------------------------------------------------------------------------
// QKV GEMM + fused epilogue (unchanged):
//   q -> L2-norm -> qb[B,H,N,64]; k -> L2-norm * 0.125*log2e*s[n] -> kb;
//   v -> fp16 transposed -> vt[B,H,64,N]
// ---------------------------------------------------------------------------
__global__ __launch_bounds__(256) void gemm_qkv(const f16* __restrict__ A,
                                                const f16* __restrict__ B,
                                                const float* __restrict__ score,
                                                f16* __restrict__ qb,
                                                f16* __restrict__ kb,
                                                f16* __restrict__ vt) {
  __shared__ __align__(16) union {
    struct { f16 As[128 * 32]; f16 Bs[128 * 32]; } s;
    f16 vtx[4][64][72];
  } sm;
  f32x4 acc[4][4];
#pragma unroll
  for (int i = 0; i < 4; ++i)
#pragma unroll
    for (int j = 0; j < 4; ++j) acc[i][j] = (f32x4){0.f, 0.f, 0.f, 0.f};

  const int bm = blockIdx.y * 128, bn = blockIdx.x * 128;
  gemm_mainloop(A, B, C_DIM, bm, bn, sm.s.As, sm.s.Bs, acc);

  const int tid = threadIdx.x;
  const int w = tid >> 6, lane = tid & 63;
  const int wm = w >> 1, wn = w & 1;
  const int ln = lane & 15, quad = lane >> 4;
  const int col0 = bn + wn * 64;
  const int mode = col0 >> 10;
  const int h    = (col0 >> 6) & 15;

  if (mode <= 1) {
    f16* dst = mode ? kb : qb;
#pragma unroll
    for (int fm = 0; fm < 4; ++fm) {
#pragma unroll
      for (int r = 0; r < 4; ++r) {
        const int m = bm + wm * 64 + fm * 16 + quad * 4 + r;
        const int b = m >> 11, n = m & (N_TOK - 1);
        float ss = acc[fm][0][r] * acc[fm][0][r] + acc[fm][1][r] * acc[fm][1][r]
                 + acc[fm][2][r] * acc[fm][2][r] + acc[fm][3][r] * acc[fm][3][r];
        ss += __shfl_xor(ss, 1, 64);
        ss += __shfl_xor(ss, 2, 64);
        ss += __shfl_xor(ss, 4, 64);
        ss += __shfl_xor(ss, 8, 64);
        float sc = 1.0f / (sqrtf(ss) + 1e-8f);
        if (mode) sc *= 0.125f * LOG2E * score[n];
        f16* drow = dst + (((size_t)(b * H_DIM + h) * N_TOK + n) << 6);
#pragma unroll
        for (int fn = 0; fn < 4; ++fn)
          drow[fn * 16 + ln] = (f16)(acc[fm][fn][r] * sc);
      }
    }
  } else {
    __syncthreads();
#pragma unroll
    for (int fm = 0; fm < 4; ++fm)
#pragma unroll
      for (int fn = 0; fn < 4; ++fn)
#pragma unroll
        for (int r = 0; r < 4; ++r)
          sm.vtx[w][fn * 16 + ln][fm * 16 + quad * 4 + r] = (f16)acc[fm][fn][r];
    const int m0 = bm + wm * 64;
    const int b = m0 >> 11, n0 = m0 & (N_TOK - 1);
    const int dg = lane >> 3;
    const int t8 = (lane & 7) << 3;
#pragma unroll
    for (int g = 0; g < 8; ++g) {
      const int d = g * 8 + dg;
      f16* drow = vt + (((size_t)(b * H_DIM + h) * HD + d) * N_TOK + n0 + t8);
      *(uint4*)drow = *(const uint4*)&sm.vtx[w][d][t8];
    }
  }
}

// ---------------------------------------------------------------------------
// Proj GEMM (unchanged)
// ---------------------------------------------------------------------------
__global__ __launch_bounds__(256) void gemm_proj(const f16* __restrict__ A,
                                                 const f16* __restrict__ B,
                                                 const float* __restrict__ bias,
                                                 float* __restrict__ out) {
  __shared__ __align__(16) struct { f16 As[128 * 32]; f16 Bs[128 * 32]; } sm;
  f32x4 acc[4][4];
#pragma unroll
  for (int i = 0; i < 4; ++i)
#pragma unroll
    for (int j = 0; j < 4; ++j) acc[i][j] = (f32x4){0.f, 0.f, 0.f, 0.f};

  const int bm = blockIdx.y * 128, bn = blockIdx.x * 128;
  gemm_mainloop(A, B, C_DIM, bm, bn, sm.As, sm.Bs, acc);

  const int tid = threadIdx.x;
  const int w = tid >> 6, lane = tid & 63;
  const int wm = w >> 1, wn = w & 1;
  const int ln = lane & 15, quad = lane >> 4;
  float bv[4];
#pragma unroll
  for (int fn = 0; fn < 4; ++fn) bv[fn] = bias[bn + wn * 64 + fn * 16 + ln];
#pragma unroll
  for (int fm = 0; fm < 4; ++fm)
#pragma unroll
    for (int r = 0; r < 4; ++r) {
      const int m = bm + wm * 64 + fm * 16 + quad * 4 + r;
#pragma unroll
      for (int fn = 0; fn < 4; ++fn)
        out[(size_t)m * C_DIM + bn + wn * 64 + fn * 16 + ln] = acc[fm][fn][r] + bv[fn];
    }
}

// ---------------------------------------------------------------------------
// MFMA attention v4. Block = 4 waves, 64 q (16 q/wave), grid (N/64, B*H).
// S^T = K.Q^T (C layout == A-frag layout of 16x16x16) -> P stays in registers.
// K A-frags double-buffered in REGISTERS, prefetched one tile ahead (fixes
// R5's exposed global latency). V staged in LDS with XOR-8 bank swizzle
// (fixes R5's 4-way even-bank conflict on the b64 PV reads).
// ---------------------------------------------------------------------------
__global__ __launch_bounds__(256, 4) void attn_mfma(const f16* __restrict__ qb,
                                                    const f16* __restrict__ kb,
                                                    const f16* __restrict__ vt,
                                                    const float* __restrict__ score,
                                                    const int* __restrict__ usem,
                                                    f16* __restrict__ obuf) {
  __shared__ __align__(16) f16 Vt[64][72];
  __shared__ float sraw[64];
  __shared__ float ls[4][16];

  const int tid  = threadIdx.x;
  const int w    = tid >> 6;
  const int lane = tid & 63;
  const int ln   = lane & 15;
  const int quad = lane >> 4;
  const int q0 = blockIdx.x * 64;
  const int bh = blockIdx.y;
  const int b  = bh >> 4, h = bh & 15;
  const int umask = *usem;

  // Q B-frags: 16 q rows per wave, held in registers
  const f16* qp = qb + ((size_t)bh * N_TOK + q0 + w * 16 + ln) * HD + quad * 8;
  const f16x8 bq0 = *(const f16x8*)(qp);
  const f16x8 bq1 = *(const f16x8*)(qp + 32);
  const float sq = score[q0 + w * 16 + ln] - 0.1f;   // per-lane query threshold

  f32x4 O[4];
#pragma unroll
  for (int t = 0; t < 4; ++t) O[t] = (f32x4){0.f, 0.f, 0.f, 0.f};
  float lpart = 0.f;

  const int sr = tid >> 2, sc = (tid & 3) << 4;
  const int sw = (sr & 1) << 3;                      // stage-write swizzle
  const f16* vbase = vt + ((size_t)bh * HD + sr) * N_TOK + sc;
  const f16* kbase = kb + (size_t)bh * N_TOK * HD;

  // prefetch V/score tile 0
  float4 vr0 = *(const float4*)(vbase);
  float4 vr1 = *(const float4*)(vbase + 8);
  float spre = score[tid & 63];

  // prefetch K tile 0 into register buffer A
  f16x8 kA0[4], kA1[4], kB0[4], kB1[4];
#pragma unroll
  for (int t = 0; t < 4; ++t) {
    const f16* kp = kbase + (size_t)(t * 16 + ln) * HD + quad * 8;
    kA0[t] = *(const f16x8*)(kp);
    kA1[t] = *(const f16x8*)(kp + 32);
  }

  auto body = [&](int k0, f16x8 (&kc0)[4], f16x8 (&kc1)[4],
                  f16x8 (&kx0)[4], f16x8 (&kx1)[4]) {
    __syncthreads();
    *(float4*)&Vt[sr][sc ^ sw]       = vr0;
    *(float4*)&Vt[sr][(sc + 8) ^ sw] = vr1;
    if (tid < 64) sraw[tid] = spre;
    __syncthreads();

    // issue ALL tile-(t+1) global loads now; consumed next iteration
    const int kn = (k0 + 64 < N_TOK) ? k0 + 64 : 0;
#pragma unroll
    for (int t = 0; t < 4; ++t) {
      const f16* kp = kbase + (size_t)(kn + t * 16 + ln) * HD + quad * 8;
      kx0[t] = *(const f16x8*)(kp);
      kx1[t] = *(const f16x8*)(kp + 32);
    }
    vr0  = *(const float4*)(vbase + kn);
    vr1  = *(const float4*)(vbase + kn + 8);
    spre = score[kn + (tid & 63)];

    // ---- S^T = K.Q^T ; softmax in-register; P stays as 16x16x16 A-frags ----
    f16x4 af[4];
#pragma unroll
    for (int t = 0; t < 4; ++t) {
      f32x4 c = (f32x4){0.f, 0.f, 0.f, 0.f};
      c = __builtin_amdgcn_mfma_f32_16x16x32_f16(kc0[t], bq0, c, 0, 0, 0);
      c = __builtin_amdgcn_mfma_f32_16x16x32_f16(kc1[t], bq1, c, 0, 0, 0);
      const float4 sk = *(const float4*)&sraw[t * 16 + quad * 4];
      const float skr[4] = {sk.x, sk.y, sk.z, sk.w};
#pragma unroll
      for (int r = 0; r < 4; ++r) {
        float x = c[r];
        if (umask && !(skr[r] > sq)) x = 0.f;
        const float p = exp2f(x);
        lpart += p;
        af[t][r] = (f16)p;
      }
    }

    // ---- O += P V via 16x16x16 (A = in-register P, B = swizzled LDS V) ----
#pragma unroll
    for (int t2 = 0; t2 < 4; ++t2)
#pragma unroll
      for (int t = 0; t < 4; ++t) {
        const f16x4 bv = *(const f16x4*)&Vt[t2 * 16 + ln][(t * 16 + quad * 4) ^ ((ln & 1) << 3)];
        O[t2] = __builtin_amdgcn_mfma_f32_16x16x16f16(af[t], bv, O[t2], 0, 0, 0);
      }
  };

  // 2x-unrolled ping-pong: register-buffer swap is free
  for (int k0 = 0; k0 < N_TOK; k0 += 128) {
    body(k0,      kA0, kA1, kB0, kB1);
    body(k0 + 64, kB0, kB1, kA0, kA1);
  }

  // ---- softmax denominators: lane holds partial for q=ln; reduce over quads ----
  float l = lpart;
  l += __shfl_xor(l, 16, 64);
  l += __shfl_xor(l, 32, 64);
  if (lane < 16) ls[w][lane] = l;     // wave-private; in-wave lgkm ordering suffices
  float inv[4];
#pragma unroll
  for (int r = 0; r < 4; ++r) inv[r] = 1.0f / ls[w][quad * 4 + r];

#pragma unroll
  for (int r = 0; r < 4; ++r) {
    const size_t row = (size_t)(b * N_TOK + q0 + w * 16 + quad * 4 + r);
#pragma unroll
    for (int t2 = 0; t2 < 4; ++t2)
      obuf[row * C_DIM + h * HD + t2 * 16 + ln] = (f16)(O[t2][r] * inv[r]);
  }
}

// ---------------------------------------------------------------------------
extern "C" void kernel_launch(void* const* d_in, const int* in_sizes, int n_in,
                              void* d_out, int out_size, void* d_ws, size_t ws_size,
                              hipStream_t stream) {
  const float* x      = (const float*)d_in[0];
  const float* score  = (const float*)d_in[1];
  const float* qkv_w  = (const float*)d_in[2];
  const float* proj_w = (const float*)d_in[3];
  const float* proj_b = (const float*)d_in[4];
  const int*   usem   = (const int*)d_in[5];
  float* out = (float*)d_out;

  f16* xh   = (f16*)d_ws;
  f16* wh   = xh  + (size_t)M_TOK * C_DIM;
  f16* pwh  = wh  + (size_t)3 * C_DIM * C_DIM;
  f16* qb   = pwh + (size_t)C_DIM * C_DIM;
  f16* kb   = qb  + (size_t)M_TOK * C_DIM;
  f16* vt   = kb  + (size_t)M_TOK * C_DIM;
  f16* obuf = vt  + (size_t)M_TOK * C_DIM;

  cvt_all<<<(CVT_X4 + CVT_W4 + CVT_P4) / 256, 256, 0, stream>>>(x, qkv_w, proj_w, xh, wh, pwh);
  {
    dim3 grid(3 * C_DIM / 128, M_TOK / 128);
    gemm_qkv<<<grid, 256, 0, stream>>>(xh, wh, score, qb, kb, vt);
  }
  {
    dim3 grid(N_TOK / 64, 2 * H_DIM);
    attn_mfma<<<grid, 256, 0, stream>>>(qb, kb, vt, score, usem, obuf);
  }
  {
    dim3 grid(C_DIM / 128, M_TOK / 128);
    gemm_proj<<<grid, 256, 0, stream>>>(obuf, pwh, proj_b, out);
  }
}

// Round 7
// 352.346 us; speedup vs baseline: 1.0100x; 1.0100x over previous
//
#include <hip/hip_runtime.h>
#include <cmath>

#define C_DIM   1024
#define H_DIM   16
#define HD      64
#define N_TOK   2048
#define M_TOK   4096
#define LOG2E   1.44269504088896340736f

typedef _Float16 f16;
typedef __attribute__((ext_vector_type(8))) _Float16 f16x8;
typedef __attribute__((ext_vector_type(4))) _Float16 f16x4;
typedef __attribute__((ext_vector_type(4))) float    f32x4;

// async global->LDS, 16B per lane; LDS dest = wave-uniform base + lane*16
__device__ __forceinline__ void gl_lds16(const void* g, void* l) {
  __builtin_amdgcn_global_load_lds((const __attribute__((address_space(1))) void*)g,
                                   (__attribute__((address_space(3))) void*)l, 16, 0, 0);
}

// ---------------------------------------------------------------------------
// fp32 -> fp16 convert: x (4.19M), qkv_w (3.15M), proj_w (1.05M), float4/thread
// ---------------------------------------------------------------------------
#define CVT_X4 1048576
#define CVT_W4 786432
#define CVT_P4 262144
__global__ __launch_bounds__(256) void cvt_all(const float* __restrict__ x,
                                               const float* __restrict__ w1,
                                               const float* __restrict__ w2,
                                               f16* __restrict__ xh,
                                               f16* __restrict__ wh1,
                                               f16* __restrict__ wh2) {
  const int i = blockIdx.x * 256 + threadIdx.x;
  const float4* src; f16* dst; int off;
  if (i < CVT_X4)               { src = (const float4*)x;  dst = xh;  off = i; }
  else if (i < CVT_X4 + CVT_W4) { src = (const float4*)w1; dst = wh1; off = i - CVT_X4; }
  else                          { src = (const float4*)w2; dst = wh2; off = i - CVT_X4 - CVT_W4; }
  const float4 v = src[off];
  union { f16 h[4]; ushort4 u; } p;
  p.h[0] = (f16)v.x; p.h[1] = (f16)v.y; p.h[2] = (f16)v.z; p.h[3] = (f16)v.w;
  *(ushort4*)(dst + (size_t)off * 4) = p.u;
}

// ---------------------------------------------------------------------------
// Shared MFMA NT-GEMM mainloop: 128x128 tile, BK=32, 4 waves (2x2), fp16.
// LDS XOR-swizzle: staging lane reads global 16B-chunk (lane&3)^((lane>>4)&3);
// ds_read column chunk quad^((ln>>2)&3). Breaks the 8-way bank conflict of the
// row-major [row][32] layout (row stride 64B) down to free 2-way.
// ---------------------------------------------------------------------------
__device__ __forceinline__ void gemm_mainloop(const f16* __restrict__ A,
                                              const f16* __restrict__ B,
                                              int K, int bm, int bn,
                                              f16* As, f16* Bs,
                                              f32x4 (&acc)[4][4]) {
  const int tid  = threadIdx.x;
  const int w    = tid >> 6, lane = tid & 63;
  const int wm   = w >> 1,   wn   = w & 1;
  const int ln   = lane & 15, quad = lane >> 4;
  const int sr   = lane >> 2;                                  // row in 16-row chunk
  const int sc   = (((lane & 3) ^ ((lane >> 4) & 3)) << 3);    // swizzled k-chunk (halves)
  const int ro   = ((quad ^ ((ln >> 2) & 3)) << 3);            // matching read swizzle

  const f16* Ag0 = A + (size_t)(bm + w * 16 + sr) * K + sc;
  const f16* Ag1 = A + (size_t)(bm + (w + 4) * 16 + sr) * K + sc;
  const f16* Bg0 = B + (size_t)(bn + w * 16 + sr) * K + sc;
  const f16* Bg1 = B + (size_t)(bn + (w + 4) * 16 + sr) * K + sc;
  f16* Al0 = As + (w * 16) * 32;
  f16* Al1 = As + ((w + 4) * 16) * 32;
  f16* Bl0 = Bs + (w * 16) * 32;
  f16* Bl1 = Bs + ((w + 4) * 16) * 32;

  for (int k0 = 0; k0 < K; k0 += 32) {
    __syncthreads();
    gl_lds16(Ag0 + k0, Al0);
    gl_lds16(Ag1 + k0, Al1);
    gl_lds16(Bg0 + k0, Bl0);
    gl_lds16(Bg1 + k0, Bl1);
    __syncthreads();
    f16x8 af[4], bf[4];
#pragma unroll
    for (int fm = 0; fm < 4; ++fm)
      af[fm] = *(const f16x8*)&As[(wm * 64 + fm * 16 + ln) * 32 + ro];
#pragma unroll
    for (int fn = 0; fn < 4; ++fn)
      bf[fn] = *(const f16x8*)&Bs[(wn * 64 + fn * 16 + ln) * 32 + ro];
#pragma unroll
    for (int fm = 0; fm < 4; ++fm)
#pragma unroll
      for (int fn = 0; fn < 4; ++fn)
        acc[fm][fn] = __builtin_amdgcn_mfma_f32_16x16x32_f16(af[fm], bf[fn], acc[fm][fn], 0, 0, 0);
  }
}

// ---------------------------------------------------------------------------
// QKV GEMM + fused epilogue:
//   q -> L2-norm -> qb[B,H,N,64]; k -> L2-norm * 0.125*log2e*s[n] -> kb;
//   v -> stored DIRECTLY in PV B-fragment order: vfrag[bh][tk][td][lane][4].
// The v-mode C-frag (lane ln,quad holds V[tok=quad*4+r][d=ln]) IS the
// mfma_16x16x16 B-frag (B[n=ln][k=quad*4+j]) -> no transpose, no LDS.
// ---------------------------------------------------------------------------
__global__ __launch_bounds__(256) void gemm_qkv(const f16* __restrict__ A,
                                                const f16* __restrict__ B,
                                                const float* __restrict__ score,
                                                f16* __restrict__ qb,
                                                f16* __restrict__ kb,
                                                f16* __restrict__ vfrag) {
  __shared__ __align__(16) struct { f16 As[128 * 32]; f16 Bs[128 * 32]; } sm;
  f32x4 acc[4][4];
#pragma unroll
  for (int i = 0; i < 4; ++i)
#pragma unroll
    for (int j = 0; j < 4; ++j) acc[i][j] = (f32x4){0.f, 0.f, 0.f, 0.f};

  const int bm = blockIdx.y * 128, bn = blockIdx.x * 128;
  gemm_mainloop(A, B, C_DIM, bm, bn, sm.As, sm.Bs, acc);

  const int tid = threadIdx.x;
  const int w = tid >> 6, lane = tid & 63;
  const int wm = w >> 1, wn = w & 1;
  const int ln = lane & 15, quad = lane >> 4;
  const int col0 = bn + wn * 64;
  const int mode = col0 >> 10;
  const int h    = (col0 >> 6) & 15;

  if (mode <= 1) {
    f16* dst = mode ? kb : qb;
#pragma unroll
    for (int fm = 0; fm < 4; ++fm) {
#pragma unroll
      for (int r = 0; r < 4; ++r) {
        const int m = bm + wm * 64 + fm * 16 + quad * 4 + r;
        const int b = m >> 11, n = m & (N_TOK - 1);
        float ss = acc[fm][0][r] * acc[fm][0][r] + acc[fm][1][r] * acc[fm][1][r]
                 + acc[fm][2][r] * acc[fm][2][r] + acc[fm][3][r] * acc[fm][3][r];
        ss += __shfl_xor(ss, 1, 64);
        ss += __shfl_xor(ss, 2, 64);
        ss += __shfl_xor(ss, 4, 64);
        ss += __shfl_xor(ss, 8, 64);
        float sc = 1.0f / (sqrtf(ss) + 1e-8f);
        if (mode) sc *= 0.125f * LOG2E * score[n];
        f16* drow = dst + (((size_t)(b * H_DIM + h) * N_TOK + n) << 6);
#pragma unroll
        for (int fn = 0; fn < 4; ++fn)
          drow[fn * 16 + ln] = (f16)(acc[fm][fn][r] * sc);
      }
    }
  } else {
    const int m0  = bm + wm * 64;
    const int b   = m0 >> 11;
    const int tk0 = (m0 & (N_TOK - 1)) >> 4;
    // halves offset: ((bh*128 + tk0+fm)*4 + fn)*256 + lane*4
    f16* vb = vfrag + (((size_t)(b * H_DIM + h) * 128 + tk0) * 4) * 256 + lane * 4;
#pragma unroll
    for (int fm = 0; fm < 4; ++fm)
#pragma unroll
      for (int fn = 0; fn < 4; ++fn) {
        f16x4 v;
#pragma unroll
        for (int r = 0; r < 4; ++r) v[r] = (f16)acc[fm][fn][r];
        *(f16x4*)(vb + ((size_t)fm * 4 + fn) * 256) = v;
      }
  }
}

// ---------------------------------------------------------------------------
// Proj GEMM (swizzled mainloop)
// ---------------------------------------------------------------------------
__global__ __launch_bounds__(256) void gemm_proj(const f16* __restrict__ A,
                                                 const f16* __restrict__ B,
                                                 const float* __restrict__ bias,
                                                 float* __restrict__ out) {
  __shared__ __align__(16) struct { f16 As[128 * 32]; f16 Bs[128 * 32]; } sm;
  f32x4 acc[4][4];
#pragma unroll
  for (int i = 0; i < 4; ++i)
#pragma unroll
    for (int j = 0; j < 4; ++j) acc[i][j] = (f32x4){0.f, 0.f, 0.f, 0.f};

  const int bm = blockIdx.y * 128, bn = blockIdx.x * 128;
  gemm_mainloop(A, B, C_DIM, bm, bn, sm.As, sm.Bs, acc);

  const int tid = threadIdx.x;
  const int w = tid >> 6, lane = tid & 63;
  const int wm = w >> 1, wn = w & 1;
  const int ln = lane & 15, quad = lane >> 4;
  float bv[4];
#pragma unroll
  for (int fn = 0; fn < 4; ++fn) bv[fn] = bias[bn + wn * 64 + fn * 16 + ln];
#pragma unroll
  for (int fm = 0; fm < 4; ++fm)
#pragma unroll
    for (int r = 0; r < 4; ++r) {
      const int m = bm + wm * 64 + fm * 16 + quad * 4 + r;
#pragma unroll
      for (int fn = 0; fn < 4; ++fn)
        out[(size_t)m * C_DIM + bn + wn * 64 + fn * 16 + ln] = acc[fm][fn][r] + bv[fn];
    }
}

// ---------------------------------------------------------------------------
// MFMA attention v5: ZERO LDS (except 256B denom xchg), ZERO barriers.
// Block = 4 waves, 64 q (16 q/wave), grid (N/64, B*H); waves free-run.
// S^T = K.Q^T (C-layout == 16x16x16 A-frag) -> P stays in registers.
// K frags from global (coalesced, L1-broadcast across the 4 waves).
// V frags from vfrag (pre-packed B-frag order: 512B coalesced broadcast loads).
// ---------------------------------------------------------------------------
__global__ __launch_bounds__(256) void attn_mfma(const f16* __restrict__ qb,
                                                 const f16* __restrict__ kb,
                                                 const f16* __restrict__ vfrag,
                                                 const float* __restrict__ score,
                                                 const int* __restrict__ usem,
                                                 f16* __restrict__ obuf) {
  __shared__ float ls[4][16];

  const int tid  = threadIdx.x;
  const int w    = tid >> 6;
  const int lane = tid & 63;
  const int ln   = lane & 15;
  const int quad = lane >> 4;
  const int q0 = blockIdx.x * 64;
  const int bh = blockIdx.y;
  const int b  = bh >> 4, h = bh & 15;
  const int umask = *usem;

  // Q B-frags: 16 q rows per wave, held in registers
  const f16* qp = qb + ((size_t)bh * N_TOK + q0 + w * 16 + ln) * HD + quad * 8;
  const f16x8 bq0 = *(const f16x8*)(qp);
  const f16x8 bq1 = *(const f16x8*)(qp + 32);
  const float sq = score[q0 + w * 16 + ln] - 0.1f;   // per-lane query threshold

  f32x4 O[4];
#pragma unroll
  for (int t = 0; t < 4; ++t) O[t] = (f32x4){0.f, 0.f, 0.f, 0.f};
  float lpart = 0.f;

  const f16* kbase = kb + ((size_t)bh * N_TOK + ln) * HD + quad * 8;
  const f16* vbase = vfrag + (size_t)bh * 128 * 1024 + (size_t)lane * 4;  // 1024 halves per tk

  for (int k0 = 0; k0 < N_TOK; k0 += 64) {
    // ---- all loads for this tile, grouped (no barriers anywhere) ----
    f16x8 ka0[4], ka1[4];
    f16x4 vf[4][4];
    float4 sk[4];
#pragma unroll
    for (int t = 0; t < 4; ++t) {
      const f16* kp = kbase + (size_t)(k0 + t * 16) * HD;
      ka0[t] = *(const f16x8*)(kp);
      ka1[t] = *(const f16x8*)(kp + 32);
      sk[t]  = *(const float4*)&score[k0 + t * 16 + quad * 4];
      const f16* vp = vbase + ((size_t)(k0 >> 4) + t) * 1024;
#pragma unroll
      for (int t2 = 0; t2 < 4; ++t2)
        vf[t][t2] = *(const f16x4*)(vp + t2 * 256);
    }

    // ---- compute: S^T tile -> softmax in-register -> PV ----
#pragma unroll
    for (int t = 0; t < 4; ++t) {
      f32x4 c = (f32x4){0.f, 0.f, 0.f, 0.f};
      c = __builtin_amdgcn_mfma_f32_16x16x32_f16(ka0[t], bq0, c, 0, 0, 0);
      c = __builtin_amdgcn_mfma_f32_16x16x32_f16(ka1[t], bq1, c, 0, 0, 0);
      const float skr[4] = {sk[t].x, sk[t].y, sk[t].z, sk[t].w};
      f16x4 af;
#pragma unroll
      for (int r = 0; r < 4; ++r) {
        float x = c[r];
        if (umask && !(skr[r] > sq)) x = 0.f;
        const float p = exp2f(x);
        lpart += p;
        af[r] = (f16)p;
      }
#pragma unroll
      for (int t2 = 0; t2 < 4; ++t2)
        O[t2] = __builtin_amdgcn_mfma_f32_16x16x16f16(af, vf[t][t2], O[t2], 0, 0, 0);
    }
  }

  // ---- softmax denominators: lane holds partial for q=ln; reduce over quads ----
  float l = lpart;
  l += __shfl_xor(l, 16, 64);
  l += __shfl_xor(l, 32, 64);
  if (lane < 16) ls[w][lane] = l;     // wave-private; in-wave lgkm ordering suffices
  float inv[4];
#pragma unroll
  for (int r = 0; r < 4; ++r) inv[r] = 1.0f / ls[w][quad * 4 + r];

#pragma unroll
  for (int r = 0; r < 4; ++r) {
    const size_t row = (size_t)(b * N_TOK + q0 + w * 16 + quad * 4 + r);
#pragma unroll
    for (int t2 = 0; t2 < 4; ++t2)
      obuf[row * C_DIM + h * HD + t2 * 16 + ln] = (f16)(O[t2][r] * inv[r]);
  }
}

// ---------------------------------------------------------------------------
extern "C" void kernel_launch(void* const* d_in, const int* in_sizes, int n_in,
                              void* d_out, int out_size, void* d_ws, size_t ws_size,
                              hipStream_t stream) {
  const float* x      = (const float*)d_in[0];
  const float* score  = (const float*)d_in[1];
  const float* qkv_w  = (const float*)d_in[2];
  const float* proj_w = (const float*)d_in[3];
  const float* proj_b = (const float*)d_in[4];
  const int*   usem   = (const int*)d_in[5];
  float* out = (float*)d_out;

  f16* xh    = (f16*)d_ws;
  f16* wh    = xh  + (size_t)M_TOK * C_DIM;
  f16* pwh   = wh  + (size_t)3 * C_DIM * C_DIM;
  f16* qb    = pwh + (size_t)C_DIM * C_DIM;
  f16* kb    = qb  + (size_t)M_TOK * C_DIM;
  f16* vfrag = kb  + (size_t)M_TOK * C_DIM;
  f16* obuf  = vfrag + (size_t)M_TOK * C_DIM;

  cvt_all<<<(CVT_X4 + CVT_W4 + CVT_P4) / 256, 256, 0, stream>>>(x, qkv_w, proj_w, xh, wh, pwh);
  {
    dim3 grid(3 * C_DIM / 128, M_TOK / 128);
    gemm_qkv<<<grid, 256, 0, stream>>>(xh, wh, score, qb, kb, vfrag);
  }
  {
    dim3 grid(N_TOK / 64, 2 * H_DIM);
    attn_mfma<<<grid, 256, 0, stream>>>(qb, kb, vfrag, score, usem, obuf);
  }
  {
    dim3 grid(C_DIM / 128, M_TOK / 128);
    gemm_proj<<<grid, 256, 0, stream>>>(obuf, pwh, proj_b, out);
  }
}

// Round 8
// 239.517 us; speedup vs baseline: 1.4858x; 1.4711x over previous
//
#include <hip/hip_runtime.h>
#include <cmath>

#define C_DIM   1024
#define H_DIM   16
#define HD      64
#define N_TOK   2048
#define M_TOK   4096
#define LOG2E   1.44269504088896340736f

typedef _Float16 f16;
typedef __attribute__((ext_vector_type(8))) _Float16 f16x8;
typedef __attribute__((ext_vector_type(4))) _Float16 f16x4;
typedef __attribute__((ext_vector_type(4))) float    f32x4;

// async global->LDS, 16B per lane; LDS dest = wave-uniform base + lane*16
__device__ __forceinline__ void gl_lds16(const void* g, void* l) {
  __builtin_amdgcn_global_load_lds((const __attribute__((address_space(1))) void*)g,
                                   (__attribute__((address_space(3))) void*)l, 16, 0, 0);
}

// ---------------------------------------------------------------------------
// fp32 -> fp16 convert: x (4.19M), qkv_w (3.15M), proj_w (1.05M), float4/thread
// ---------------------------------------------------------------------------
#define CVT_X4 1048576
#define CVT_W4 786432
#define CVT_P4 262144
__global__ __launch_bounds__(256) void cvt_all(const float* __restrict__ x,
                                               const float* __restrict__ w1,
                                               const float* __restrict__ w2,
                                               f16* __restrict__ xh,
                                               f16* __restrict__ wh1,
                                               f16* __restrict__ wh2) {
  const int i = blockIdx.x * 256 + threadIdx.x;
  const float4* src; f16* dst; int off;
  if (i < CVT_X4)               { src = (const float4*)x;  dst = xh;  off = i; }
  else if (i < CVT_X4 + CVT_W4) { src = (const float4*)w1; dst = wh1; off = i - CVT_X4; }
  else                          { src = (const float4*)w2; dst = wh2; off = i - CVT_X4 - CVT_W4; }
  const float4 v = src[off];
  union { f16 h[4]; ushort4 u; } p;
  p.h[0] = (f16)v.x; p.h[1] = (f16)v.y; p.h[2] = (f16)v.z; p.h[3] = (f16)v.w;
  *(ushort4*)(dst + (size_t)off * 4) = p.u;
}

// ---------------------------------------------------------------------------
// Shared MFMA NT-GEMM mainloop: 128x128 tile, BK=32, 4 waves (2x2), fp16.
// LDS XOR-swizzle breaks the 8-way conflict of row-major [row][32] layout.
// ---------------------------------------------------------------------------
__device__ __forceinline__ void gemm_mainloop(const f16* __restrict__ A,
                                              const f16* __restrict__ B,
                                              int K, int bm, int bn,
                                              f16* As, f16* Bs,
                                              f32x4 (&acc)[4][4]) {
  const int tid  = threadIdx.x;
  const int w    = tid >> 6, lane = tid & 63;
  const int wm   = w >> 1,   wn   = w & 1;
  const int ln   = lane & 15, quad = lane >> 4;
  const int sr   = lane >> 2;                                  // row in 16-row chunk
  const int sc   = (((lane & 3) ^ ((lane >> 4) & 3)) << 3);    // swizzled k-chunk (halves)
  const int ro   = ((quad ^ ((ln >> 2) & 3)) << 3);            // matching read swizzle

  const f16* Ag0 = A + (size_t)(bm + w * 16 + sr) * K + sc;
  const f16* Ag1 = A + (size_t)(bm + (w + 4) * 16 + sr) * K + sc;
  const f16* Bg0 = B + (size_t)(bn + w * 16 + sr) * K + sc;
  const f16* Bg1 = B + (size_t)(bn + (w + 4) * 16 + sr) * K + sc;
  f16* Al0 = As + (w * 16) * 32;
  f16* Al1 = As + ((w + 4) * 16) * 32;
  f16* Bl0 = Bs + (w * 16) * 32;
  f16* Bl1 = Bs + ((w + 4) * 16) * 32;

  for (int k0 = 0; k0 < K; k0 += 32) {
    __syncthreads();
    gl_lds16(Ag0 + k0, Al0);
    gl_lds16(Ag1 + k0, Al1);
    gl_lds16(Bg0 + k0, Bl0);
    gl_lds16(Bg1 + k0, Bl1);
    __syncthreads();
    f16x8 af[4], bf[4];
#pragma unroll
    for (int fm = 0; fm < 4; ++fm)
      af[fm] = *(const f16x8*)&As[(wm * 64 + fm * 16 + ln) * 32 + ro];
#pragma unroll
    for (int fn = 0; fn < 4; ++fn)
      bf[fn] = *(const f16x8*)&Bs[(wn * 64 + fn * 16 + ln) * 32 + ro];
#pragma unroll
    for (int fm = 0; fm < 4; ++fm)
#pragma unroll
      for (int fn = 0; fn < 4; ++fn)
        acc[fm][fn] = __builtin_amdgcn_mfma_f32_16x16x32_f16(af[fm], bf[fn], acc[fm][fn], 0, 0, 0);
  }
}

// ---------------------------------------------------------------------------
// QKV GEMM + fused epilogue:
//   q -> L2-norm -> qb[B,H,N,64]; k -> L2-norm * 0.125*log2e*s[n] -> kb;
//   v -> PV B-frag order: vfrag[bh][tk][p][lane][{fn&1}*4+r], 16B/lane chunks.
// v-mode C-frag (lane holds V[tok=quad*4+r][d=fn*16+ln]) IS the 16x16x16
// B-frag -> pack fn pairs into one f16x8, fully coalesced 16B stores.
// ---------------------------------------------------------------------------
__global__ __launch_bounds__(256) void gemm_qkv(const f16* __restrict__ A,
                                                const f16* __restrict__ B,
                                                const float* __restrict__ score,
                                                f16* __restrict__ qb,
                                                f16* __restrict__ kb,
                                                f16* __restrict__ vfrag) {
  __shared__ __align__(16) struct { f16 As[128 * 32]; f16 Bs[128 * 32]; } sm;
  f32x4 acc[4][4];
#pragma unroll
  for (int i = 0; i < 4; ++i)
#pragma unroll
    for (int j = 0; j < 4; ++j) acc[i][j] = (f32x4){0.f, 0.f, 0.f, 0.f};

  const int bm = blockIdx.y * 128, bn = blockIdx.x * 128;
  gemm_mainloop(A, B, C_DIM, bm, bn, sm.As, sm.Bs, acc);

  const int tid = threadIdx.x;
  const int w = tid >> 6, lane = tid & 63;
  const int wm = w >> 1, wn = w & 1;
  const int ln = lane & 15, quad = lane >> 4;
  const int col0 = bn + wn * 64;
  const int mode = col0 >> 10;
  const int h    = (col0 >> 6) & 15;

  if (mode <= 1) {
    f16* dst = mode ? kb : qb;
#pragma unroll
    for (int fm = 0; fm < 4; ++fm) {
#pragma unroll
      for (int r = 0; r < 4; ++r) {
        const int m = bm + wm * 64 + fm * 16 + quad * 4 + r;
        const int b = m >> 11, n = m & (N_TOK - 1);
        float ss = acc[fm][0][r] * acc[fm][0][r] + acc[fm][1][r] * acc[fm][1][r]
                 + acc[fm][2][r] * acc[fm][2][r] + acc[fm][3][r] * acc[fm][3][r];
        ss += __shfl_xor(ss, 1, 64);
        ss += __shfl_xor(ss, 2, 64);
        ss += __shfl_xor(ss, 4, 64);
        ss += __shfl_xor(ss, 8, 64);
        float sc = 1.0f / (sqrtf(ss) + 1e-8f);
        if (mode) sc *= 0.125f * LOG2E * score[n];
        f16* drow = dst + (((size_t)(b * H_DIM + h) * N_TOK + n) << 6);
#pragma unroll
        for (int fn = 0; fn < 4; ++fn)
          drow[fn * 16 + ln] = (f16)(acc[fm][fn][r] * sc);
      }
    }
  } else {
    const int m0  = bm + wm * 64;
    const int b   = m0 >> 11;
    const int tk0 = (m0 & (N_TOK - 1)) >> 4;
    // halves offset: ((bh*128 + tk)*2 + p)*512 + lane*8
    f16* vb = vfrag + (((size_t)(b * H_DIM + h) * 128 + tk0) * 2) * 512 + lane * 8;
#pragma unroll
    for (int fm = 0; fm < 4; ++fm)
#pragma unroll
      for (int p = 0; p < 2; ++p) {
        f16x8 v8;
#pragma unroll
        for (int r = 0; r < 4; ++r) v8[r]     = (f16)acc[fm][2 * p][r];
#pragma unroll
        for (int r = 0; r < 4; ++r) v8[4 + r] = (f16)acc[fm][2 * p + 1][r];
        *(f16x8*)(vb + ((size_t)fm * 2 + p) * 512) = v8;
      }
  }
}

// ---------------------------------------------------------------------------
// Proj GEMM (swizzled mainloop)
// ---------------------------------------------------------------------------
__global__ __launch_bounds__(256) void gemm_proj(const f16* __restrict__ A,
                                                 const f16* __restrict__ B,
                                                 const float* __restrict__ bias,
                                                 float* __restrict__ out) {
  __shared__ __align__(16) struct { f16 As[128 * 32]; f16 Bs[128 * 32]; } sm;
  f32x4 acc[4][4];
#pragma unroll
  for (int i = 0; i < 4; ++i)
#pragma unroll
    for (int j = 0; j < 4; ++j) acc[i][j] = (f32x4){0.f, 0.f, 0.f, 0.f};

  const int bm = blockIdx.y * 128, bn = blockIdx.x * 128;
  gemm_mainloop(A, B, C_DIM, bm, bn, sm.As, sm.Bs, acc);

  const int tid = threadIdx.x;
  const int w = tid >> 6, lane = tid & 63;
  const int wm = w >> 1, wn = w & 1;
  const int ln = lane & 15, quad = lane >> 4;
  float bv[4];
#pragma unroll
  for (int fn = 0; fn < 4; ++fn) bv[fn] = bias[bn + wn * 64 + fn * 16 + ln];
#pragma unroll
  for (int fm = 0; fm < 4; ++fm)
#pragma unroll
    for (int r = 0; r < 4; ++r) {
      const int m = bm + wm * 64 + fm * 16 + quad * 4 + r;
#pragma unroll
      for (int fn = 0; fn < 4; ++fn)
        out[(size_t)m * C_DIM + bn + wn * 64 + fn * 16 + ln] = acc[fm][fn][r] + bv[fn];
    }
}

// ---------------------------------------------------------------------------
// MFMA attention v6: LDS-staged K/V (dedups the 4-wave operand redundancy
// that made v5 L1-bound), double-buffered, ONE barrier per tile.
//  - V: prepacked frag order -> gl_lds16 DMA, conflict-free lane*16 b128 reads
//  - K: global->reg prefetch -> pad-72 LDS (2-way = free)
//  - S^T = K.Q^T: P stays in registers (C-layout == 16x16x16 A-frag)
//  - row-sum l via all-ones B-frag on the MFMA pipe (no VALU adds/shuffles)
// ---------------------------------------------------------------------------
__global__ __launch_bounds__(256) void attn_mfma(const f16* __restrict__ qb,
                                                 const f16* __restrict__ kb,
                                                 const f16* __restrict__ vfrag,
                                                 const float* __restrict__ score,
                                                 const int* __restrict__ usem,
                                                 f16* __restrict__ obuf) {
  __shared__ __align__(16) f16 Kl[2][64][72];
  __shared__ __align__(16) f16 Vl[2][4096];

  const int tid  = threadIdx.x;
  const int w    = tid >> 6;
  const int lane = tid & 63;
  const int ln   = lane & 15;
  const int quad = lane >> 4;
  const int q0 = blockIdx.x * 64;
  const int bh = blockIdx.y;
  const int b  = bh >> 4, h = bh & 15;
  const int umask = *usem;

  // Q B-frags: 16 q rows per wave, in registers for the whole kernel
  const f16* qp = qb + ((size_t)bh * N_TOK + q0 + w * 16 + ln) * HD + quad * 8;
  const f16x8 bq0 = *(const f16x8*)(qp);
  const f16x8 bq1 = *(const f16x8*)(qp + 32);
  const float sq = score[q0 + w * 16 + ln] - 0.1f;

  f32x4 O[4], Ol;
#pragma unroll
  for (int t = 0; t < 4; ++t) O[t] = (f32x4){0.f, 0.f, 0.f, 0.f};
  Ol = (f32x4){0.f, 0.f, 0.f, 0.f};
  const f16x4 ones = (f16x4){(f16)1.f, (f16)1.f, (f16)1.f, (f16)1.f};

  const int sr  = tid >> 2;            // K stage row 0..63
  const int scc = (tid & 3) << 4;      // K stage col (halves)
  const int c0  = 2 * w, c1 = 2 * w + 1;   // V DMA chunks for this wave
  const f16* kg = kb    + (size_t)bh * N_TOK * HD;
  const f16* vg = vfrag + (size_t)bh * 128 * 1024;

  // ---- prologue: stage tile 0 into buffer 0 ----
  gl_lds16(vg + c0 * 512 + lane * 8, &Vl[0][c0 * 512]);
  gl_lds16(vg + c1 * 512 + lane * 8, &Vl[0][c1 * 512]);
  {
    const float4 k0r = *(const float4*)(kg + (size_t)sr * HD + scc);
    const float4 k1r = *(const float4*)(kg + (size_t)sr * HD + scc + 8);
    *(float4*)&Kl[0][sr][scc]     = k0r;
    *(float4*)&Kl[0][sr][scc + 8] = k1r;
  }
  __syncthreads();

  auto body = [&](int k0, int cur, int nxt) {
    // ---- prefetch tile t+1: V via DMA into nxt, K into registers ----
    const int kn = (k0 + 64 < N_TOK) ? k0 + 64 : 0;
    const f16* vt = vg + (size_t)(kn >> 4) * 1024;
    gl_lds16(vt + c0 * 512 + lane * 8, &Vl[nxt][c0 * 512]);
    gl_lds16(vt + c1 * 512 + lane * 8, &Vl[nxt][c1 * 512]);
    const float4 kn0 = *(const float4*)(kg + (size_t)(kn + sr) * HD + scc);
    const float4 kn1 = *(const float4*)(kg + (size_t)(kn + sr) * HD + scc + 8);

    // ---- S^T = K.Q^T from Kl[cur] ----
    f16x4 af[4];
    f32x4 c[4];
#pragma unroll
    for (int t = 0; t < 4; ++t) {
      const f16x8 ka0 = *(const f16x8*)&Kl[cur][t * 16 + ln][quad * 8];
      const f16x8 ka1 = *(const f16x8*)&Kl[cur][t * 16 + ln][32 + quad * 8];
      f32x4 cc = (f32x4){0.f, 0.f, 0.f, 0.f};
      cc = __builtin_amdgcn_mfma_f32_16x16x32_f16(ka0, bq0, cc, 0, 0, 0);
      cc = __builtin_amdgcn_mfma_f32_16x16x32_f16(ka1, bq1, cc, 0, 0, 0);
      c[t] = cc;
    }

    // ---- softmax in-register (log2 domain; masked -> exp2(0)=1) ----
#pragma unroll
    for (int t = 0; t < 4; ++t) {
      const float4 sk = *(const float4*)&score[k0 + t * 16 + quad * 4];
      const float skr[4] = {sk.x, sk.y, sk.z, sk.w};
#pragma unroll
      for (int r = 0; r < 4; ++r) {
        float x = c[t][r];
        if (umask && !(skr[r] > sq)) x = 0.f;
        af[t][r] = (f16)exp2f(x);
      }
    }

    // ---- O += P V from Vl[cur]; l accumulated via ones-frag MFMA ----
#pragma unroll
    for (int t = 0; t < 4; ++t) {
      Ol = __builtin_amdgcn_mfma_f32_16x16x16f16(af[t], ones, Ol, 0, 0, 0);
#pragma unroll
      for (int p = 0; p < 2; ++p) {
        const f16x8 vv = *(const f16x8*)&Vl[cur][(t * 2 + p) * 512 + lane * 8];
        const f16x4 vlo = __builtin_shufflevector(vv, vv, 0, 1, 2, 3);
        const f16x4 vhi = __builtin_shufflevector(vv, vv, 4, 5, 6, 7);
        O[2 * p]     = __builtin_amdgcn_mfma_f32_16x16x16f16(af[t], vlo, O[2 * p], 0, 0, 0);
        O[2 * p + 1] = __builtin_amdgcn_mfma_f32_16x16x16f16(af[t], vhi, O[2 * p + 1], 0, 0, 0);
      }
    }

    // ---- stage prefetched K into Kl[nxt]; barrier flips buffers ----
    *(float4*)&Kl[nxt][sr][scc]     = kn0;
    *(float4*)&Kl[nxt][sr][scc + 8] = kn1;
    __syncthreads();   // compiler drains vmcnt (DMA) + lgkm before barrier
  };

  for (int k0 = 0; k0 < N_TOK; k0 += 128) {
    body(k0, 0, 1);
    body(k0 + 64, 1, 0);
  }

  // ---- epilogue: l for q=quad*4+r sits in Ol[r] on every lane ----
#pragma unroll
  for (int r = 0; r < 4; ++r) {
    const float inv = 1.0f / Ol[r];
    const size_t row = (size_t)(b * N_TOK + q0 + w * 16 + quad * 4 + r);
#pragma unroll
    for (int t2 = 0; t2 < 4; ++t2)
      obuf[row * C_DIM + h * HD + t2 * 16 + ln] = (f16)(O[t2][r] * inv);
  }
}

// ---------------------------------------------------------------------------
extern "C" void kernel_launch(void* const* d_in, const int* in_sizes, int n_in,
                              void* d_out, int out_size, void* d_ws, size_t ws_size,
                              hipStream_t stream) {
  const float* x      = (const float*)d_in[0];
  const float* score  = (const float*)d_in[1];
  const float* qkv_w  = (const float*)d_in[2];
  const float* proj_w = (const float*)d_in[3];
  const float* proj_b = (const float*)d_in[4];
  const int*   usem   = (const int*)d_in[5];
  float* out = (float*)d_out;

  f16* xh    = (f16*)d_ws;
  f16* wh    = xh  + (size_t)M_TOK * C_DIM;
  f16* pwh   = wh  + (size_t)3 * C_DIM * C_DIM;
  f16* qb    = pwh + (size_t)C_DIM * C_DIM;
  f16* kb    = qb  + (size_t)M_TOK * C_DIM;
  f16* vfrag = kb  + (size_t)M_TOK * C_DIM;
  f16* obuf  = vfrag + (size_t)M_TOK * C_DIM;

  cvt_all<<<(CVT_X4 + CVT_W4 + CVT_P4) / 256, 256, 0, stream>>>(x, qkv_w, proj_w, xh, wh, pwh);
  {
    dim3 grid(3 * C_DIM / 128, M_TOK / 128);
    gemm_qkv<<<grid, 256, 0, stream>>>(xh, wh, score, qb, kb, vfrag);
  }
  {
    dim3 grid(N_TOK / 64, 2 * H_DIM);
    attn_mfma<<<grid, 256, 0, stream>>>(qb, kb, vfrag, score, usem, obuf);
  }
  {
    dim3 grid(C_DIM / 128, M_TOK / 128);
    gemm_proj<<<grid, 256, 0, stream>>>(obuf, pwh, proj_b, out);
  }
}

// Round 9
// 228.465 us; speedup vs baseline: 1.5577x; 1.0484x over previous
//
#include <hip/hip_runtime.h>
#include <cmath>

#define C_DIM   1024
#define H_DIM   16
#define HD      64
#define N_TOK   2048
#define M_TOK   4096
#define LOG2E   1.44269504088896340736f

typedef _Float16 f16;
typedef __attribute__((ext_vector_type(8))) _Float16 f16x8;
typedef __attribute__((ext_vector_type(4))) _Float16 f16x4;
typedef __attribute__((ext_vector_type(4))) float    f32x4;

// async global->LDS, 16B per lane; LDS dest = wave-uniform base + lane*16
__device__ __forceinline__ void gl_lds16(const void* g, void* l) {
  __builtin_amdgcn_global_load_lds((const __attribute__((address_space(1))) void*)g,
                                   (__attribute__((address_space(3))) void*)l, 16, 0, 0);
}

// ---------------------------------------------------------------------------
// fp32 -> fp16 convert: x (4.19M), qkv_w (3.15M), proj_w (1.05M), float4/thread
// ---------------------------------------------------------------------------
#define CVT_X4 1048576
#define CVT_W4 786432
#define CVT_P4 262144
__global__ __launch_bounds__(256) void cvt_all(const float* __restrict__ x,
                                               const float* __restrict__ w1,
                                               const float* __restrict__ w2,
                                               f16* __restrict__ xh,
                                               f16* __restrict__ wh1,
                                               f16* __restrict__ wh2) {
  const int i = blockIdx.x * 256 + threadIdx.x;
  const float4* src; f16* dst; int off;
  if (i < CVT_X4)               { src = (const float4*)x;  dst = xh;  off = i; }
  else if (i < CVT_X4 + CVT_W4) { src = (const float4*)w1; dst = wh1; off = i - CVT_X4; }
  else                          { src = (const float4*)w2; dst = wh2; off = i - CVT_X4 - CVT_W4; }
  const float4 v = src[off];
  union { f16 h[4]; ushort4 u; } p;
  p.h[0] = (f16)v.x; p.h[1] = (f16)v.y; p.h[2] = (f16)v.z; p.h[3] = (f16)v.w;
  *(ushort4*)(dst + (size_t)off * 4) = p.u;
}

// ---------------------------------------------------------------------------
// Shared MFMA NT-GEMM mainloop: 128x128 tile, 4 waves (2x2), fp16.
// TWO BK=32 sub-tiles staged per barrier pair (16 barrier rounds for K=1024,
// halving the vmcnt(0)+s_barrier drain count vs the BK=32 loop).
// ---------------------------------------------------------------------------
#define SUB (128 * 32)   // halves per sub-tile

__device__ __forceinline__ void gemm_mainloop(const f16* __restrict__ A,
                                              const f16* __restrict__ B,
                                              int K, int bm, int bn,
                                              f16* As, f16* Bs,
                                              f32x4 (&acc)[4][4]) {
  const int tid  = threadIdx.x;
  const int w    = tid >> 6, lane = tid & 63;
  const int wm   = w >> 1,   wn   = w & 1;
  const int ln   = lane & 15, quad = lane >> 4;
  const int sr   = lane >> 2;                                  // row in 16-row chunk
  const int sc   = (((lane & 3) ^ ((lane >> 4) & 3)) << 3);    // swizzled k-chunk (halves)
  const int ro   = ((quad ^ ((ln >> 2) & 3)) << 3);            // matching read swizzle

  const f16* Ag0 = A + (size_t)(bm + w * 16 + sr) * K + sc;
  const f16* Ag1 = A + (size_t)(bm + (w + 4) * 16 + sr) * K + sc;
  const f16* Bg0 = B + (size_t)(bn + w * 16 + sr) * K + sc;
  const f16* Bg1 = B + (size_t)(bn + (w + 4) * 16 + sr) * K + sc;
  f16* Al0 = As + (w * 16) * 32;
  f16* Al1 = As + ((w + 4) * 16) * 32;
  f16* Bl0 = Bs + (w * 16) * 32;
  f16* Bl1 = Bs + ((w + 4) * 16) * 32;

  for (int k0 = 0; k0 < K; k0 += 64) {
    __syncthreads();
    gl_lds16(Ag0 + k0, Al0);
    gl_lds16(Ag1 + k0, Al1);
    gl_lds16(Bg0 + k0, Bl0);
    gl_lds16(Bg1 + k0, Bl1);
    gl_lds16(Ag0 + k0 + 32, Al0 + SUB);
    gl_lds16(Ag1 + k0 + 32, Al1 + SUB);
    gl_lds16(Bg0 + k0 + 32, Bl0 + SUB);
    gl_lds16(Bg1 + k0 + 32, Bl1 + SUB);
    __syncthreads();
#pragma unroll
    for (int s = 0; s < 2; ++s) {
      const f16* Asub = As + s * SUB;
      const f16* Bsub = Bs + s * SUB;
      f16x8 af[4], bf[4];
#pragma unroll
      for (int fm = 0; fm < 4; ++fm)
        af[fm] = *(const f16x8*)&Asub[(wm * 64 + fm * 16 + ln) * 32 + ro];
#pragma unroll
      for (int fn = 0; fn < 4; ++fn)
        bf[fn] = *(const f16x8*)&Bsub[(wn * 64 + fn * 16 + ln) * 32 + ro];
#pragma unroll
      for (int fm = 0; fm < 4; ++fm)
#pragma unroll
        for (int fn = 0; fn < 4; ++fn)
          acc[fm][fn] = __builtin_amdgcn_mfma_f32_16x16x32_f16(af[fm], bf[fn], acc[fm][fn], 0, 0, 0);
    }
  }
}

// ---------------------------------------------------------------------------
// QKV GEMM + fused epilogue:
//   q -> L2-norm -> qb[B,H,N,64]; k -> L2-norm * 0.125*log2e*s[n] -> kb;
//   v -> PV B-frag order: vfrag[bh][tk][p][lane][8], 16B/lane chunks.
// ---------------------------------------------------------------------------
__global__ __launch_bounds__(256) void gemm_qkv(const f16* __restrict__ A,
                                                const f16* __restrict__ B,
                                                const float* __restrict__ score,
                                                f16* __restrict__ qb,
                                                f16* __restrict__ kb,
                                                f16* __restrict__ vfrag) {
  __shared__ __align__(16) struct { f16 As[2 * SUB]; f16 Bs[2 * SUB]; } sm;
  f32x4 acc[4][4];
#pragma unroll
  for (int i = 0; i < 4; ++i)
#pragma unroll
    for (int j = 0; j < 4; ++j) acc[i][j] = (f32x4){0.f, 0.f, 0.f, 0.f};

  const int bm = blockIdx.y * 128, bn = blockIdx.x * 128;
  gemm_mainloop(A, B, C_DIM, bm, bn, sm.As, sm.Bs, acc);

  const int tid = threadIdx.x;
  const int w = tid >> 6, lane = tid & 63;
  const int wm = w >> 1, wn = w & 1;
  const int ln = lane & 15, quad = lane >> 4;
  const int col0 = bn + wn * 64;
  const int mode = col0 >> 10;
  const int h    = (col0 >> 6) & 15;

  if (mode <= 1) {
    f16* dst = mode ? kb : qb;
#pragma unroll
    for (int fm = 0; fm < 4; ++fm) {
#pragma unroll
      for (int r = 0; r < 4; ++r) {
        const int m = bm + wm * 64 + fm * 16 + quad * 4 + r;
        const int b = m >> 11, n = m & (N_TOK - 1);
        float ss = acc[fm][0][r] * acc[fm][0][r] + acc[fm][1][r] * acc[fm][1][r]
                 + acc[fm][2][r] * acc[fm][2][r] + acc[fm][3][r] * acc[fm][3][r];
        ss += __shfl_xor(ss, 1, 64);
        ss += __shfl_xor(ss, 2, 64);
        ss += __shfl_xor(ss, 4, 64);
        ss += __shfl_xor(ss, 8, 64);
        float sc = 1.0f / (sqrtf(ss) + 1e-8f);
        if (mode) sc *= 0.125f * LOG2E * score[n];
        f16* drow = dst + (((size_t)(b * H_DIM + h) * N_TOK + n) << 6);
#pragma unroll
        for (int fn = 0; fn < 4; ++fn)
          drow[fn * 16 + ln] = (f16)(acc[fm][fn][r] * sc);
      }
    }
  } else {
    const int m0  = bm + wm * 64;
    const int b   = m0 >> 11;
    const int tk0 = (m0 & (N_TOK - 1)) >> 4;
    f16* vb = vfrag + (((size_t)(b * H_DIM + h) * 128 + tk0) * 2) * 512 + lane * 8;
#pragma unroll
    for (int fm = 0; fm < 4; ++fm)
#pragma unroll
      for (int p = 0; p < 2; ++p) {
        f16x8 v8;
#pragma unroll
        for (int r = 0; r < 4; ++r) v8[r]     = (f16)acc[fm][2 * p][r];
#pragma unroll
        for (int r = 0; r < 4; ++r) v8[4 + r] = (f16)acc[fm][2 * p + 1][r];
        *(f16x8*)(vb + ((size_t)fm * 2 + p) * 512) = v8;
      }
  }
}

// ---------------------------------------------------------------------------
// Proj GEMM
// ---------------------------------------------------------------------------
__global__ __launch_bounds__(256) void gemm_proj(const f16* __restrict__ A,
                                                 const f16* __restrict__ B,
                                                 const float* __restrict__ bias,
                                                 float* __restrict__ out) {
  __shared__ __align__(16) struct { f16 As[2 * SUB]; f16 Bs[2 * SUB]; } sm;
  f32x4 acc[4][4];
#pragma unroll
  for (int i = 0; i < 4; ++i)
#pragma unroll
    for (int j = 0; j < 4; ++j) acc[i][j] = (f32x4){0.f, 0.f, 0.f, 0.f};

  const int bm = blockIdx.y * 128, bn = blockIdx.x * 128;
  gemm_mainloop(A, B, C_DIM, bm, bn, sm.As, sm.Bs, acc);

  const int tid = threadIdx.x;
  const int w = tid >> 6, lane = tid & 63;
  const int wm = w >> 1, wn = w & 1;
  const int ln = lane & 15, quad = lane >> 4;
  float bv[4];
#pragma unroll
  for (int fn = 0; fn < 4; ++fn) bv[fn] = bias[bn + wn * 64 + fn * 16 + ln];
#pragma unroll
  for (int fm = 0; fm < 4; ++fm)
#pragma unroll
    for (int r = 0; r < 4; ++r) {
      const int m = bm + wm * 64 + fm * 16 + quad * 4 + r;
#pragma unroll
      for (int fn = 0; fn < 4; ++fn)
        out[(size_t)m * C_DIM + bn + wn * 64 + fn * 16 + ln] = acc[fm][fn][r] + bv[fn];
    }
}

// ---------------------------------------------------------------------------
// MFMA attention v7 = v6 + XCD-pinned grid.
// grid = (B*H, N/64): blockIdx.x = bh -> XCD (bh%8) hosts only 4 bh's K/V
// (2 MB < 4 MB L2) -> staging loads are L2-hot, barrier drain shrinks.
// ---------------------------------------------------------------------------
__global__ __launch_bounds__(256) void attn_mfma(const f16* __restrict__ qb,
                                                 const f16* __restrict__ kb,
                                                 const f16* __restrict__ vfrag,
                                                 const float* __restrict__ score,
                                                 const int* __restrict__ usem,
                                                 f16* __restrict__ obuf) {
  __shared__ __align__(16) f16 Kl[2][64][72];
  __shared__ __align__(16) f16 Vl[2][4096];

  const int tid  = threadIdx.x;
  const int w    = tid >> 6;
  const int lane = tid & 63;
  const int ln   = lane & 15;
  const int quad = lane >> 4;
  const int bh = blockIdx.x;                 // XCD-pinned: bh%8
  const int q0 = blockIdx.y * 64;
  const int b  = bh >> 4, h = bh & 15;
  const int umask = *usem;

  // Q B-frags: 16 q rows per wave, in registers for the whole kernel
  const f16* qp = qb + ((size_t)bh * N_TOK + q0 + w * 16 + ln) * HD + quad * 8;
  const f16x8 bq0 = *(const f16x8*)(qp);
  const f16x8 bq1 = *(const f16x8*)(qp + 32);
  const float sq = score[q0 + w * 16 + ln] - 0.1f;

  f32x4 O[4], Ol;
#pragma unroll
  for (int t = 0; t < 4; ++t) O[t] = (f32x4){0.f, 0.f, 0.f, 0.f};
  Ol = (f32x4){0.f, 0.f, 0.f, 0.f};
  const f16x4 ones = (f16x4){(f16)1.f, (f16)1.f, (f16)1.f, (f16)1.f};

  const int sr  = tid >> 2;            // K stage row 0..63
  const int scc = (tid & 3) << 4;      // K stage col (halves)
  const int c0  = 2 * w, c1 = 2 * w + 1;   // V DMA chunks for this wave
  const f16* kg = kb    + (size_t)bh * N_TOK * HD;
  const f16* vg = vfrag + (size_t)bh * 128 * 1024;

  // ---- prologue: stage tile 0 into buffer 0 ----
  gl_lds16(vg + c0 * 512 + lane * 8, &Vl[0][c0 * 512]);
  gl_lds16(vg + c1 * 512 + lane * 8, &Vl[0][c1 * 512]);
  {
    const float4 k0r = *(const float4*)(kg + (size_t)sr * HD + scc);
    const float4 k1r = *(const float4*)(kg + (size_t)sr * HD + scc + 8);
    *(float4*)&Kl[0][sr][scc]     = k0r;
    *(float4*)&Kl[0][sr][scc + 8] = k1r;
  }
  __syncthreads();

  auto body = [&](int k0, int cur, int nxt) {
    // ---- prefetch tile t+1: V via DMA into nxt, K into registers ----
    const int kn = (k0 + 64 < N_TOK) ? k0 + 64 : 0;
    const f16* vt = vg + (size_t)(kn >> 4) * 1024;
    gl_lds16(vt + c0 * 512 + lane * 8, &Vl[nxt][c0 * 512]);
    gl_lds16(vt + c1 * 512 + lane * 8, &Vl[nxt][c1 * 512]);
    const float4 kn0 = *(const float4*)(kg + (size_t)(kn + sr) * HD + scc);
    const float4 kn1 = *(const float4*)(kg + (size_t)(kn + sr) * HD + scc + 8);

    // ---- S^T = K.Q^T from Kl[cur] ----
    f16x4 af[4];
    f32x4 c[4];
#pragma unroll
    for (int t = 0; t < 4; ++t) {
      const f16x8 ka0 = *(const f16x8*)&Kl[cur][t * 16 + ln][quad * 8];
      const f16x8 ka1 = *(const f16x8*)&Kl[cur][t * 16 + ln][32 + quad * 8];
      f32x4 cc = (f32x4){0.f, 0.f, 0.f, 0.f};
      cc = __builtin_amdgcn_mfma_f32_16x16x32_f16(ka0, bq0, cc, 0, 0, 0);
      cc = __builtin_amdgcn_mfma_f32_16x16x32_f16(ka1, bq1, cc, 0, 0, 0);
      c[t] = cc;
    }

    // ---- softmax in-register (log2 domain; masked -> exp2(0)=1) ----
#pragma unroll
    for (int t = 0; t < 4; ++t) {
      const float4 sk = *(const float4*)&score[k0 + t * 16 + quad * 4];
      const float skr[4] = {sk.x, sk.y, sk.z, sk.w};
#pragma unroll
      for (int r = 0; r < 4; ++r) {
        float x = c[t][r];
        if (umask && !(skr[r] > sq)) x = 0.f;
        af[t][r] = (f16)exp2f(x);
      }
    }

    // ---- O += P V from Vl[cur]; l accumulated via ones-frag MFMA ----
#pragma unroll
    for (int t = 0; t < 4; ++t) {
      Ol = __builtin_amdgcn_mfma_f32_16x16x16f16(af[t], ones, Ol, 0, 0, 0);
#pragma unroll
      for (int p = 0; p < 2; ++p) {
        const f16x8 vv = *(const f16x8*)&Vl[cur][(t * 2 + p) * 512 + lane * 8];
        const f16x4 vlo = __builtin_shufflevector(vv, vv, 0, 1, 2, 3);
        const f16x4 vhi = __builtin_shufflevector(vv, vv, 4, 5, 6, 7);
        O[2 * p]     = __builtin_amdgcn_mfma_f32_16x16x16f16(af[t], vlo, O[2 * p], 0, 0, 0);
        O[2 * p + 1] = __builtin_amdgcn_mfma_f32_16x16x16f16(af[t], vhi, O[2 * p + 1], 0, 0, 0);
      }
    }

    // ---- stage prefetched K into Kl[nxt]; barrier flips buffers ----
    *(float4*)&Kl[nxt][sr][scc]     = kn0;
    *(float4*)&Kl[nxt][sr][scc + 8] = kn1;
    __syncthreads();
  };

  for (int k0 = 0; k0 < N_TOK; k0 += 128) {
    body(k0, 0, 1);
    body(k0 + 64, 1, 0);
  }

  // ---- epilogue: l for q=quad*4+r sits in Ol[r] on every lane ----
#pragma unroll
  for (int r = 0; r < 4; ++r) {
    const float inv = 1.0f / Ol[r];
    const size_t row = (size_t)(b * N_TOK + q0 + w * 16 + quad * 4 + r);
#pragma unroll
    for (int t2 = 0; t2 < 4; ++t2)
      obuf[row * C_DIM + h * HD + t2 * 16 + ln] = (f16)(O[t2][r] * inv);
  }
}

// ---------------------------------------------------------------------------
extern "C" void kernel_launch(void* const* d_in, const int* in_sizes, int n_in,
                              void* d_out, int out_size, void* d_ws, size_t ws_size,
                              hipStream_t stream) {
  const float* x      = (const float*)d_in[0];
  const float* score  = (const float*)d_in[1];
  const float* qkv_w  = (const float*)d_in[2];
  const float* proj_w = (const float*)d_in[3];
  const float* proj_b = (const float*)d_in[4];
  const int*   usem   = (const int*)d_in[5];
  float* out = (float*)d_out;

  f16* xh    = (f16*)d_ws;
  f16* wh    = xh  + (size_t)M_TOK * C_DIM;
  f16* pwh   = wh  + (size_t)3 * C_DIM * C_DIM;
  f16* qb    = pwh + (size_t)C_DIM * C_DIM;
  f16* kb    = qb  + (size_t)M_TOK * C_DIM;
  f16* vfrag = kb  + (size_t)M_TOK * C_DIM;
  f16* obuf  = vfrag + (size_t)M_TOK * C_DIM;

  cvt_all<<<(CVT_X4 + CVT_W4 + CVT_P4) / 256, 256, 0, stream>>>(x, qkv_w, proj_w, xh, wh, pwh);
  {
    dim3 grid(3 * C_DIM / 128, M_TOK / 128);
    gemm_qkv<<<grid, 256, 0, stream>>>(xh, wh, score, qb, kb, vfrag);
  }
  {
    dim3 grid(2 * H_DIM, N_TOK / 64);   // bh fastest -> XCD-pinned K/V
    attn_mfma<<<grid, 256, 0, stream>>>(qb, kb, vfrag, score, usem, obuf);
  }
  {
    dim3 grid(C_DIM / 128, M_TOK / 128);
    gemm_proj<<<grid, 256, 0, stream>>>(obuf, pwh, proj_b, out);
  }
}